// Round 3
// baseline (248.952 us; speedup 1.0000x reference)
//
#include <hip/hip_runtime.h>
#include <math.h>

// B=2048, S=8, D=1280, K=1 rank-1 common-mode removal.
// Fully fused: 1 wave per batch, the 8x1280 fp32 slice lives in registers
// (8 rows x 5 float4/lane = 160 VGPRs). feat read ONCE, out written ONCE.
// Gram + 8x8 top-eigenpair entirely via wave shuffles; no LDS, no barriers.

#define SV 8
#define DV 1280
#define D4 (DV/4)          // 320 float4 per row
#define BSTRIDE (SV*DV)    // 10240 floats per batch

__global__ __launch_bounds__(256, 2)   // cap 256 VGPR -> 2 waves/SIMD
void cmr_fused_kernel(const float* __restrict__ feat,
                      const float* __restrict__ kp,
                      const float* __restrict__ cmr_gate,
                      float* __restrict__ out,
                      int Bn)
{
    const int lane = threadIdx.x & 63;
    const int b = blockIdx.x * 4 + (threadIdx.x >> 6);   // 1 wave = 1 batch

    // ---- 1. load the whole batch slice into registers (40 x 16B coalesced) ----
    const float4* __restrict__ f4 = (const float4*)(feat + (size_t)b * BSTRIDE);
    float4 f[8][5];
#pragma unroll
    for (int k = 0; k < 5; ++k) {
        const int d4 = lane + 64 * k;
#pragma unroll
        for (int s = 0; s < 8; ++s) f[s][k] = f4[s * D4 + d4];
    }

    // ---- 2. raw row sums + upper-tri cross products from registers ----
    float Sr[8], C[36];
#pragma unroll
    for (int s = 0; s < 8; ++s) Sr[s] = 0.f;
#pragma unroll
    for (int t = 0; t < 36; ++t) C[t] = 0.f;
#pragma unroll
    for (int k = 0; k < 5; ++k) {
#pragma unroll
        for (int s = 0; s < 8; ++s)
            Sr[s] += (f[s][k].x + f[s][k].y) + (f[s][k].z + f[s][k].w);
        int idx = 0;
#pragma unroll
        for (int i = 0; i < 8; ++i)
#pragma unroll
            for (int j = i; j < 8; ++j) {
                float t0 = fmaf(f[i][k].x, f[j][k].x, fmaf(f[i][k].y, f[j][k].y, 0.f));
                float t1 = fmaf(f[i][k].z, f[j][k].z, fmaf(f[i][k].w, f[j][k].w, t0));
                C[idx] += t1; ++idx;
            }
    }
    // butterfly-reduce all 44 partials across the wave (all lanes get totals)
#pragma unroll
    for (int m = 32; m >= 1; m >>= 1) {
#pragma unroll
        for (int s = 0; s < 8; ++s) Sr[s] += __shfl_xor(Sr[s], m);
#pragma unroll
        for (int t = 0; t < 36; ++t) C[t] += __shfl_xor(C[t], m);
    }

    // ---- 3. lane (i,j) builds its normalized Gram entry G[i][j] ----
    const int i = lane >> 3, j = lane & 7;
    const int a_ = (i < j) ? i : j;
    const int b_ = (i < j) ? j : i;
    const int tii = 8 * i - (i * (i - 1)) / 2;
    const int tjj = 8 * j - (j * (j - 1)) / 2;
    const int tij = 8 * a_ - (a_ * (a_ - 1)) / 2 + (b_ - a_);

    float Ci = 0.f, Cj = 0.f, Cij = 0.f, Si = 0.f, Sj = 0.f;
#pragma unroll
    for (int t = 0; t < 36; ++t) {
        Ci  = (t == tii) ? C[t] : Ci;
        Cj  = (t == tjj) ? C[t] : Cj;
        Cij = (t == tij) ? C[t] : Cij;
    }
#pragma unroll
    for (int s = 0; s < 8; ++s) {
        Si = (s == i) ? Sr[s] : Si;
        Sj = (s == j) ? Sr[s] : Sj;
    }
    const float invD = 1.f / (float)DV;
    const float mui = Si * invD, muj = Sj * invD;
    const float vari = fmaxf(Ci * invD - mui * mui, 0.f);
    const float varj = fmaxf(Cj * invD - muj * muj, 0.f);
    const float sigi = sqrtf(vari) + 1e-8f;          // numpy std(ddof=0)+1e-8
    const float rsigi = 1.f / sigi;
    const float rsigj = 1.f / (sqrtf(varj) + 1e-8f);
    const float G = ((Cij - (float)DV * mui * muj) * rsigi) * rsigj;

    // trace (= sum of squared singular values)
    float tr = (i == j) ? G : 0.f;
#pragma unroll
    for (int m = 32; m >= 1; m >>= 1) tr += __shfl_xor(tr, m);
    const float trs = fmaxf(tr, 1e-30f);

    // ---- 4. top eigenpair: 14x trace-normalized squaring + polish ----
    float A = G / trs;
#pragma unroll
    for (int t = 0; t < 14; ++t) {
        float nb = 0.f;
#pragma unroll
        for (int k = 0; k < 8; ++k)
            nb = fmaf(__shfl(A, i * 8 + k), __shfl(A, k * 8 + j), nb);
        float dg = (i == j) ? nb : 0.f;
#pragma unroll
        for (int m = 32; m >= 1; m >>= 1) dg += __shfl_xor(dg, m);
        A = nb / fmaxf(dg, 1e-30f);
    }
    // argmax over diagonal -> dominant column ~ u1
    float dv = (i == j) ? A : -1.f;
    int bj = j;
#pragma unroll
    for (int m = 32; m >= 1; m >>= 1) {
        float ov = __shfl_xor(dv, m);
        int   oj = __shfl_xor(bj, m);
        if (ov > dv) { dv = ov; bj = oj; }
    }
    float u = __shfl(A, i * 8 + bj);                 // ~u_i (all lanes of row i)
    {
        float nn = (j == 0) ? u * u : 0.f;
#pragma unroll
        for (int m = 32; m >= 1; m >>= 1) nn += __shfl_xor(nn, m);
        u *= rsqrtf(fmaxf(nn, 1e-30f));
    }
    // 2 power-iteration polish steps on G
#pragma unroll
    for (int it = 0; it < 2; ++it) {
        float y = G * __shfl(u, j * 8);              // G[i][j]*u_j
#pragma unroll
        for (int m = 1; m <= 4; m <<= 1) y += __shfl_xor(y, m);   // -> y_i
        float ny = (j == 0) ? y * y : 0.f;
#pragma unroll
        for (int m = 32; m >= 1; m >>= 1) ny += __shfl_xor(ny, m);
        u = y * rsqrtf(fmaxf(ny, 1e-30f));
    }
    // Rayleigh quotient
    float lp = G * u * __shfl(u, j * 8);
#pragma unroll
    for (int m = 32; m >= 1; m >>= 1) lp += __shfl_xor(lp, m);
    const float pc1 = lp / (tr + 1e-8f);

    // gates
    const float gate = 1.f / (1.f + expf(-cmr_gate[0]));
    const float kpg  = (kp[b] >= 5.0f) ? 1.5f : 1.0f;
    const float Gt   = gate * kpg;

    // bconst = sum_s u_s * rsig_s * mu_s  (butterfly -> all lanes)
    float bc = (j == 0) ? u * rsigi * mui : 0.f;
#pragma unroll
    for (int m = 32; m >= 1; m >>= 1) bc += __shfl_xor(bc, m);

    // broadcast per-row coefficients to all lanes (from lane s*8, where i==s)
    const float av = u * rsigi;        // a_i   : p = sum a_s f[s,d] - bc
    const float cv = Gt * sigi * u;    // coef_i: out = f - coef_s * p
    float a[8], c[8];
#pragma unroll
    for (int s = 0; s < 8; ++s) {
        a[s] = __shfl(av, s * 8);
        c[s] = __shfl(cv, s * 8);
    }

    // ---- 5. apply from registers, store once ----
    float4* __restrict__ o4 = (float4*)(out + (size_t)b * BSTRIDE);
#pragma unroll
    for (int k = 0; k < 5; ++k) {
        const int d4 = lane + 64 * k;
        float4 p = make_float4(-bc, -bc, -bc, -bc);
#pragma unroll
        for (int s = 0; s < 8; ++s) {
            p.x = fmaf(a[s], f[s][k].x, p.x);
            p.y = fmaf(a[s], f[s][k].y, p.y);
            p.z = fmaf(a[s], f[s][k].z, p.z);
            p.w = fmaf(a[s], f[s][k].w, p.w);
        }
#pragma unroll
        for (int s = 0; s < 8; ++s) {
            float4 o;
            o.x = fmaf(-c[s], p.x, f[s][k].x);
            o.y = fmaf(-c[s], p.y, f[s][k].y);
            o.z = fmaf(-c[s], p.z, f[s][k].z);
            o.w = fmaf(-c[s], p.w, f[s][k].w);
            o4[s * D4 + d4] = o;
        }
    }

    if (lane == 0) {
        out[(size_t)Bn * BSTRIDE + b] = pc1;
        const float flag = (pc1 >= 0.6f ? 1.f : 0.f) + (pc1 >= 0.8f ? 1.f : 0.f);
        out[(size_t)Bn * BSTRIDE + Bn + b] = flag;
    }
}

extern "C" void kernel_launch(void* const* d_in, const int* in_sizes, int n_in,
                              void* d_out, int out_size, void* d_ws, size_t ws_size,
                              hipStream_t stream) {
    const float* feat = (const float*)d_in[0];
    const float* kp   = (const float*)d_in[1];
    const float* gate = (const float*)d_in[2];
    const int Bn = in_sizes[0] / BSTRIDE;       // 2048
    cmr_fused_kernel<<<Bn / 4, 256, 0, stream>>>(feat, kp, gate, (float*)d_out, Bn);
}

// Round 4
// 177.094 us; speedup vs baseline: 1.4058x; 1.4058x over previous
//
#include <hip/hip_runtime.h>
#include <math.h>

// B=2048, S=8, D=1280, K=1 rank-1 common-mode removal.
// K1: block = batch (320 thr, 5 waves = 5 column chunks). Vectorized float4
//     loads -> 44 Gram/sum partials -> 3-round butterfly -> tiny LDS -> wave0
//     solves the 8x8 top-eigenpair (gather-shuffle trace renorm) -> coeffs to ws.
// K2: pure streaming apply (feat L3-warm), coeffs via uniform scalar loads.
// No register residency across serial phases (R3 spilled); no big LDS (R1).

#define SV 8
#define DV 1280
#define D4 320             // float4 per row
#define BSTRIDE (SV*DV)    // 10240 floats per batch
#define LDW 44             // padded partial stride (floats); 40 used
#define WSS 17             // per-batch coeffs: a[8], coef[8], bconst

__global__ __launch_bounds__(320)
void cmr_stats(const float* __restrict__ feat,
               const float* __restrict__ kp,
               const float* __restrict__ cmr_gate,
               float* __restrict__ cws,
               float* __restrict__ out,
               int Bn)
{
    __shared__ float lds[44 * LDW];       // 7744 B
    const int tid  = threadIdx.x;
    const int lane = tid & 63;
    const int wq   = tid >> 6;            // 0..4 = column chunk
    const int b    = blockIdx.x;

    // ---- load: 8 float4 per lane, fully coalesced ----
    const float4* __restrict__ f4 = (const float4*)(feat + (size_t)b * BSTRIDE);
    const int d4 = wq * 64 + lane;
    float4 f[8];
#pragma unroll
    for (int s = 0; s < 8; ++s) f[s] = f4[s * D4 + d4];

    // ---- 44 partials: 36 upper-tri cross products + 8 row sums ----
    float Sr[8], C[36];
#pragma unroll
    for (int s = 0; s < 8; ++s) Sr[s] = (f[s].x + f[s].y) + (f[s].z + f[s].w);
    {
        int idx = 0;
#pragma unroll
        for (int i2 = 0; i2 < 8; ++i2)
#pragma unroll
            for (int j2 = i2; j2 < 8; ++j2) {
                float t0 = fmaf(f[i2].x, f[j2].x, fmaf(f[i2].y, f[j2].y, 0.f));
                C[idx] = fmaf(f[i2].z, f[j2].z, fmaf(f[i2].w, f[j2].w, t0));
                ++idx;
            }
    }
    // 3-round butterfly -> 8 representatives per wave hold 8-lane-group totals
#pragma unroll
    for (int m = 1; m <= 4; m <<= 1) {
#pragma unroll
        for (int s = 0; s < 8; ++s) Sr[s] += __shfl_xor(Sr[s], m);
#pragma unroll
        for (int t = 0; t < 36; ++t) C[t] += __shfl_xor(C[t], m);
    }
    {
        const int p = wq * 8 + (lane >> 3);   // 0..39
        if ((lane & 7) == 0) {
#pragma unroll
            for (int t = 0; t < 36; ++t) lds[t * LDW + p] = C[t];
#pragma unroll
            for (int s = 0; s < 8; ++s) lds[(36 + s) * LDW + p] = Sr[s];
        }
    }
    __syncthreads();
    if (wq != 0) return;

    // ---- wave 0: sum 40 partials per value (lane L owns value L, L<44) ----
    float tot;
    {
        const float4* l4 = (const float4*)lds;
        const int Lr = (lane < 44) ? lane : 0;
        float4 a4 = make_float4(0.f, 0.f, 0.f, 0.f);
#pragma unroll
        for (int q = 0; q < 10; ++q) {
            float4 v = l4[Lr * (LDW / 4) + q];
            a4.x += v.x; a4.y += v.y; a4.z += v.z; a4.w += v.w;
        }
        tot = (a4.x + a4.y) + (a4.z + a4.w);
    }

    // ---- lane (i,j) builds normalized Gram entry via gather shuffles ----
    const int i = lane >> 3, j = lane & 7;
    const int a_ = (i < j) ? i : j;
    const int b_ = (i < j) ? j : i;
    const int tii = 8 * i - (i * (i - 1)) / 2;
    const int tjj = 8 * j - (j * (j - 1)) / 2;
    const int tij = 8 * a_ - (a_ * (a_ - 1)) / 2 + (b_ - a_);
    const float Cij = __shfl(tot, tij);
    const float Ci  = __shfl(tot, tii);
    const float Cj  = __shfl(tot, tjj);
    const float Si  = __shfl(tot, 36 + i);
    const float Sj  = __shfl(tot, 36 + j);

    const float invD = 1.f / (float)DV;
    const float mui = Si * invD, muj = Sj * invD;
    const float vari = fmaxf(Ci * invD - mui * mui, 0.f);
    const float varj = fmaxf(Cj * invD - muj * muj, 0.f);
    const float sigi  = sqrtf(vari) + 1e-8f;       // numpy std(ddof=0)+1e-8
    const float rsigi = 1.f / sigi;
    const float rsigj = 1.f / (sqrtf(varj) + 1e-8f);
    const float G = ((Cij - (float)DV * mui * muj) * rsigi) * rsigj;

    // trace via 8-gather (diag lives on lanes 9k)
    float tr = 0.f;
#pragma unroll
    for (int k = 0; k < 8; ++k) tr += __shfl(G, 9 * k);

    // ---- 14x trace-normalized squaring (|A_ij| <= trace: overflow-proof) ----
    float A = G / fmaxf(tr, 1e-30f);
#pragma unroll
    for (int t = 0; t < 14; ++t) {
        float nb = 0.f;
#pragma unroll
        for (int k = 0; k < 8; ++k)
            nb = fmaf(__shfl(A, i * 8 + k), __shfl(A, k * 8 + j), nb);
        float dg = 0.f;
#pragma unroll
        for (int k = 0; k < 8; ++k) dg += __shfl(nb, 9 * k);
        A = nb / fmaxf(dg, 1e-30f);
    }
    // argmax over diagonal (uniform across lanes) -> dominant column ~ u1
    float best = __shfl(A, 0); int bj = 0;
#pragma unroll
    for (int k = 1; k < 8; ++k) {
        float dk = __shfl(A, 9 * k);
        if (dk > best) { best = dk; bj = k; }
    }
    float u = __shfl(A, i * 8 + bj);               // u_i on all lanes of row i
    {
        float nn = 0.f;
#pragma unroll
        for (int k = 0; k < 8; ++k) nn += __shfl(u * u, 9 * k);
        u *= rsqrtf(fmaxf(nn, 1e-30f));
    }
    // 2 power-iteration polish steps on G
#pragma unroll
    for (int it = 0; it < 2; ++it) {
        float y = G * __shfl(u, 9 * j);            // G[i][j] * u_j
#pragma unroll
        for (int m = 1; m <= 4; m <<= 1) y += __shfl_xor(y, m);  // row sum -> y_i
        float ny = 0.f;
#pragma unroll
        for (int k = 0; k < 8; ++k) ny += __shfl(y * y, 9 * k);
        u = y * rsqrtf(fmaxf(ny, 1e-30f));
    }
    // Rayleigh quotient lambda1 = u^T G u
    float v = G * u * __shfl(u, 9 * j);
#pragma unroll
    for (int m = 1; m <= 4; m <<= 1) v += __shfl_xor(v, m);
    float lam = 0.f;
#pragma unroll
    for (int k = 0; k < 8; ++k) lam += __shfl(v, 9 * k);
    const float pc1 = lam / (tr + 1e-8f);

    // gates
    const float gate = 1.f / (1.f + expf(-cmr_gate[0]));
    const float kpg  = (kp[b] >= 5.0f) ? 1.5f : 1.0f;
    const float Gt   = gate * kpg;

    // bconst = sum_s u_s * rsig_s * mu_s (gather from diag lanes)
    float bc = 0.f;
#pragma unroll
    for (int k = 0; k < 8; ++k) bc += __shfl(u * rsigi * mui, 9 * k);

    float* wsb = cws + (size_t)b * WSS;
    if (j == 0) {
        wsb[i]     = u * rsigi;        // a_i   : p = sum a_s f[s,d] - bc
        wsb[8 + i] = Gt * sigi * u;    // coef_i: out = f - coef_s * p
    }
    if (lane == 0) {
        wsb[16] = bc;
        out[(size_t)Bn * BSTRIDE + b] = pc1;
        const float flag = (pc1 >= 0.6f ? 1.f : 0.f) + (pc1 >= 0.8f ? 1.f : 0.f);
        out[(size_t)Bn * BSTRIDE + Bn + b] = flag;
    }
}

__global__ __launch_bounds__(320)
void cmr_apply(const float* __restrict__ feat,
               const float* __restrict__ cws,
               float* __restrict__ out)
{
    const int tid  = threadIdx.x;
    const int lane = tid & 63;
    const int wq   = tid >> 6;
    const int b    = blockIdx.x;

    // uniform address per block -> scalar loads
    const float* __restrict__ wsb = cws + (size_t)b * WSS;
    float a[8], c[8];
#pragma unroll
    for (int s = 0; s < 8; ++s) { a[s] = wsb[s]; c[s] = wsb[8 + s]; }
    const float bc = wsb[16];

    const float4* __restrict__ f4 = (const float4*)(feat + (size_t)b * BSTRIDE);
    float4* __restrict__ o4 = (float4*)(out + (size_t)b * BSTRIDE);
    const int d4 = wq * 64 + lane;

    float4 f[8];
#pragma unroll
    for (int s = 0; s < 8; ++s) f[s] = f4[s * D4 + d4];

    float4 p = make_float4(-bc, -bc, -bc, -bc);
#pragma unroll
    for (int s = 0; s < 8; ++s) {
        p.x = fmaf(a[s], f[s].x, p.x);
        p.y = fmaf(a[s], f[s].y, p.y);
        p.z = fmaf(a[s], f[s].z, p.z);
        p.w = fmaf(a[s], f[s].w, p.w);
    }
#pragma unroll
    for (int s = 0; s < 8; ++s) {
        float4 o;
        o.x = fmaf(-c[s], p.x, f[s].x);
        o.y = fmaf(-c[s], p.y, f[s].y);
        o.z = fmaf(-c[s], p.z, f[s].z);
        o.w = fmaf(-c[s], p.w, f[s].w);
        o4[s * D4 + d4] = o;
    }
}

extern "C" void kernel_launch(void* const* d_in, const int* in_sizes, int n_in,
                              void* d_out, int out_size, void* d_ws, size_t ws_size,
                              hipStream_t stream) {
    const float* feat = (const float*)d_in[0];
    const float* kp   = (const float*)d_in[1];
    const float* gate = (const float*)d_in[2];
    float* out = (float*)d_out;
    float* cws = (float*)d_ws;
    const int Bn = in_sizes[0] / BSTRIDE;       // 2048

    cmr_stats<<<Bn, 320, 0, stream>>>(feat, kp, gate, cws, out, Bn);
    cmr_apply<<<Bn, 320, 0, stream>>>(feat, cws, out);
}